// Round 2
// baseline (702.798 us; speedup 1.0000x reference)
//
#include <hip/hip_runtime.h>

#define NN 100000
#define NE 1600000
#define NB 391                      // ceil(NN/256)
#define EDGE_BLK 1563               // ceil(NE/1024), 4 edges/thread
#define MM_BLK 3125                 // NN/32 tiles
#define NXCD 8
#define FIXSCALE 68719476736.0f     // 2^36
#define FIXINV   (1.0 / 68719476736.0)
#define MASK48   0xFFFFFFFFFFFFULL

// ---------------- shared GEMM tile body:  out[32 x 128] = x_tile @ W -------
// norm factors are folded into CSR edge weights, so this is a PURE gemm.
// Ws is a 16-row K-chunk (8 KB): total LDS 24.7 KB -> 6 blocks/CU.
__device__ __forceinline__ void matmul_tile(const float* __restrict__ x,
                                            const float* __restrict__ W,
                                            float* __restrict__ out,
                                            int tile, int tid,
                                            float (*xs)[129], float (*Ws)[128])
{
    int r = tid & 31, cg = tid >> 5;
    float acc[16];
#pragma unroll
    for (int i = 0; i < 16; i++) acc[i] = 0.f;

#pragma unroll
    for (int i = 0; i < 4; i++) {
        int idx = tid + i * 256;
        int rr = idx >> 5;
        int c4 = (idx & 31) << 2;
        *(float4*)&xs[rr][c4] =
            *(const float4*)(x + (size_t)(tile * 32 + rr) * 128 + c4);
    }

#pragma unroll
    for (int kh = 0; kh < 8; kh++) {
        __syncthreads();
#pragma unroll
        for (int i = 0; i < 2; i++) {
            int idx = tid + i * 256;
            int kk = idx >> 5;              // 0..15
            int c4 = (idx & 31) << 2;
            *(float4*)&Ws[kk][c4] =
                *(const float4*)(W + (size_t)(kh * 16 + kk) * 128 + c4);
        }
        __syncthreads();
#pragma unroll
        for (int k = 0; k < 16; k++) {
            float xk = xs[r][kh * 16 + k];
            const float* wr = &Ws[k][cg * 16];
#pragma unroll
            for (int jj = 0; jj < 16; jj++)
                acc[jj] = fmaf(xk, wr[jj], acc[jj]);
        }
    }

    float* op = out + (size_t)(tile * 32 + r) * 128 + cg * 16;
#pragma unroll
    for (int i = 0; i < 4; i++)
        *(float4*)(op + i * 4) =
            make_float4(acc[i*4], acc[i*4+1], acc[i*4+2], acc[i*4+3]);
}

// ---------------- kernel 1: FUSED edge pipeline + layer-1 GEMM -------------
// R1 post-mortem: device-scope atomics saturated at ~16 G/s independent of
// occupancy -> the coherence-point (IF-side) pipe is the limiter. R2: 8
// per-XCD partial tables; each block reads its physical XCD id (HW_REG_XCC_ID,
// HW-verified 0..7 on MI355X) and uses WORKGROUP-scope atomics, which execute
// in the local XCD L2 (no sc1 bypass): ~3x lower latency, 8 L2s in parallel.
// Correct: each table is only ever touched through one XCD's L2; kernel-end
// release flushes L2 for the downstream kernels. CSR slot = per-(xcd,dst)
// segment slot, packed into pos_e as (xcc<<13)|slot.
__global__ __launch_bounds__(256) void fused1_kernel(
        const float* __restrict__ ef,
        const float* __restrict__ W_ef,
        const float* __restrict__ b_ef,
        const int* __restrict__ src,
        const int* __restrict__ dst,
        float* __restrict__ w_raw,
        unsigned short* __restrict__ pos_e,
        unsigned long long* __restrict__ outp,   // [NXCD][NN]
        unsigned long long* __restrict__ inp,    // [NXCD][NN]
        const float* __restrict__ node_feats,
        const float* __restrict__ W1,
        float* __restrict__ t_buf)
{
    __shared__ float xs[32][129];     // +1 pad: kills stride-128 bank conflict
    __shared__ float Ws[16][128];     // 16-row K-chunk: 8 KB
    int tid = threadIdx.x;

    if (blockIdx.x < EDGE_BLK) {
        int xcc;
        asm volatile("s_getreg_b32 %0, hwreg(HW_REG_XCC_ID)" : "=s"(xcc));
        xcc &= 7;
        unsigned long long* mo = outp + (size_t)xcc * NN;
        unsigned long long* mi = inp  + (size_t)xcc * NN;

        int base = blockIdx.x * 1024 + tid;
        unsigned long long old[4];
        int eok[4], dsts[4];
#pragma unroll
        for (int q = 0; q < 4; q++) {
            int e = base + q * 256;
            eok[q] = (e < NE);
            if (!eok[q]) continue;
            const float4* p = (const float4*)(ef + (size_t)e * 16);
            float acc = b_ef[0];
#pragma unroll
            for (int i = 0; i < 4; i++) {
                float4 v = p[i];
                acc += v.x * W_ef[i*4+0] + v.y * W_ef[i*4+1]
                     + v.z * W_ef[i*4+2] + v.w * W_ef[i*4+3];
            }
            w_raw[e] = acc;
            unsigned long long pk = (1ULL << 48) |
                (unsigned long long)(acc * FIXSCALE);
            __hip_atomic_fetch_add(&mo[src[e]], pk,
                                   __ATOMIC_RELAXED, __HIP_MEMORY_SCOPE_WORKGROUP);
            dsts[q] = dst[e];
            old[q] = __hip_atomic_fetch_add(&mi[dsts[q]], pk,
                                   __ATOMIC_RELAXED, __HIP_MEMORY_SCOPE_WORKGROUP);
        }
#pragma unroll
        for (int q = 0; q < 4; q++) {
            int e = base + q * 256;
            if (eok[q])
                pos_e[e] = (unsigned short)(((unsigned)xcc << 13) |
                                            (unsigned)(old[q] >> 48));
        }
        return;
    }

    matmul_tile(node_feats, W1, t_buf, blockIdx.x - EDGE_BLK, tid, xs, Ws);
}

// ---------------- kernel 2: combine per-XCD partials -> per-node factors ---
// Sums the 8 partial (count,fixsum) pairs per direction, computes
// fo = norm_out/sqrt(dout_w), fi = norm_in/sqrt(din_w), emits din totals and
// the 8-way exclusive segment offsets (loc_off) used by the CSR scatter.
// Fixed-point regrouping is bit-identical to the single-table version.
__global__ __launch_bounds__(256) void node_norm_kernel(
        const unsigned long long* __restrict__ outp,   // [NXCD][NN]
        const unsigned long long* __restrict__ inp,    // [NXCD][NN]
        float* __restrict__ fo, float* __restrict__ fi,
        unsigned short* __restrict__ loc_off,          // [NXCD][NN]
        int* __restrict__ din_buf,
        int* __restrict__ blk_sums)
{
    __shared__ int red[256];
    int t = threadIdx.x;
    int n = blockIdx.x * 256 + t;
    int din = 0;
    if (n < NN) {
        unsigned long long so = 0, si = 0;
        int dout = 0, run = 0;
#pragma unroll
        for (int x = 0; x < NXCD; x++) {
            unsigned long long po = outp[(size_t)x * NN + n];
            unsigned long long pi = inp [(size_t)x * NN + n];
            dout += (int)(po >> 48);
            so   += po & MASK48;
            loc_off[(size_t)x * NN + n] = (unsigned short)run;  // exclusive
            run  += (int)(pi >> 48);
            si   += pi & MASK48;
        }
        din = run;
        din_buf[n] = din;
        float wo = (float)((double)so * FIXINV);
        float wi = (float)((double)si * FIXINV);
        float no = 1.0f / sqrtf((float)(dout > 1 ? dout : 1));
        float ni = 1.0f / sqrtf((float)(din  > 1 ? din  : 1));
        fo[n] = (wo > 0.f) ? no / sqrtf(wo) : 0.f;
        fi[n] = (wi > 0.f) ? ni / sqrtf(wi) : 0.f;
    }
    red[t] = din;
    __syncthreads();
#pragma unroll
    for (int s = 128; s > 0; s >>= 1) {
        if (t < s) red[t] += red[t + s];
        __syncthreads();
    }
    if (t == 0) blk_sums[blockIdx.x] = red[0];
}

// ---------------- kernel 3a: exclusive scan of 391 block sums --------------
__global__ void scan_blk_kernel(const int* __restrict__ blk_sums,
                                int* __restrict__ blk_off)
{
    __shared__ int s[512];
    int t = threadIdx.x;
    int v = (t < NB) ? blk_sums[t] : 0;
    s[t] = v;
    __syncthreads();
    for (int o = 1; o < 512; o <<= 1) {
        int u = (t >= o) ? s[t - o] : 0;
        __syncthreads();
        s[t] += u;
        __syncthreads();
    }
    if (t < NB) blk_off[t] = s[t] - v;   // exclusive
}

// ---------------- kernel 3b: block-local scan -> row_ptr -------------------
__global__ __launch_bounds__(256) void row_ptr_kernel(
        const int* __restrict__ din_buf,
        const int* __restrict__ blk_off,
        int* __restrict__ row_ptr)
{
    __shared__ int s[256];
    int t = threadIdx.x;
    int n = blockIdx.x * 256 + t;
    int d = (n < NN) ? din_buf[n] : 0;
    s[t] = d;
    __syncthreads();
    for (int o = 1; o < 256; o <<= 1) {
        int u = (t >= o) ? s[t - o] : 0;
        __syncthreads();
        s[t] += u;
        __syncthreads();
    }
    if (n < NN) {
        int rp = blk_off[blockIdx.x] + s[t] - d;   // exclusive
        row_ptr[n] = rp;
        if (n == NN - 1) row_ptr[NN] = rp + d;     // == NE
    }
}

// ---------------- kernel 4: CSR scatter with fully-folded weights ----------
__global__ void scatter_kernel(const float* __restrict__ w_raw,
                               const unsigned short* __restrict__ pos_e,
                               const int* __restrict__ src,
                               const int* __restrict__ dst,
                               const float* __restrict__ fo,
                               const float* __restrict__ fi,
                               const int* __restrict__ row_ptr,
                               const unsigned short* __restrict__ loc_off,
                               int2* __restrict__ csr)
{
    int e = blockIdx.x * blockDim.x + threadIdx.x;
    if (e >= NE) return;
    int s = src[e], d = dst[e];
    unsigned pe = pos_e[e];
    int xcc = pe >> 13, slot = pe & 0x1FFF;
    float wn = w_raw[e] * fo[s] * fi[d];
    int pos = row_ptr[d] + (int)loc_off[(size_t)xcc * NN + d] + slot;
    csr[pos] = make_int2(s, __float_as_int(wn));
}

// ---------------- kernel 5: standalone pure GEMM (layer 2) -----------------
__global__ __launch_bounds__(256) void matmul_kernel(
        const float* __restrict__ x,
        const float* __restrict__ W,
        float* __restrict__ out)
{
    __shared__ float xs[32][129];
    __shared__ float Ws[16][128];
    matmul_tile(x, W, out, blockIdx.x, threadIdx.x, xs, Ws);
}

// ---------------- kernel 6: CSR SpMM, wave per row, shfl-broadcast + ILP ---
template <bool RELU>
__global__ __launch_bounds__(256) void spmm_kernel(
        const float* __restrict__ t,
        const int* __restrict__ row_ptr,
        const int2* __restrict__ csr,
        const float* __restrict__ bias,
        float* __restrict__ out)
{
    int gtid = blockIdx.x * blockDim.x + threadIdx.x;
    int row = gtid >> 6;
    int lane = threadIdx.x & 63;
    if (row >= NN) return;
    int start = row_ptr[row], end = row_ptr[row + 1];
    float ax = 0.f, ay = 0.f;
    const float* tl = t + lane * 2;
    for (int base = start; base < end; base += 64) {
        int idx = base + lane;
        int2 pr = (idx < end) ? csr[idx] : make_int2(0, 0);
        int cnt = end - base; if (cnt > 64) cnt = 64;
        int cnt8 = (cnt + 7) & ~7;
        for (int j = 0; j < cnt8; j += 8) {
#pragma unroll
            for (int u = 0; u < 8; u++) {
                int s = __shfl(pr.x, j + u);
                float w = __int_as_float(__shfl(pr.y, j + u));
                float2 hv = *(const float2*)(tl + ((size_t)s << 7));
                ax = fmaf(w, hv.x, ax);
                ay = fmaf(w, hv.y, ay);
            }
        }
    }
    float ox = ax + bias[lane * 2];
    float oy = ay + bias[lane * 2 + 1];
    if (RELU) { ox = ox > 0.f ? ox : 0.f; oy = oy > 0.f ? oy : 0.f; }
    *(float2*)(out + ((size_t)row << 7) + lane * 2) = make_float2(ox, oy);
}

// ---------------------------------------------------------------------------
extern "C" void kernel_launch(void* const* d_in, const int* in_sizes, int n_in,
                              void* d_out, int out_size, void* d_ws, size_t ws_size,
                              hipStream_t stream)
{
    const float* node_feats = (const float*)d_in[0];
    const float* edge_feats = (const float*)d_in[1];
    const float* W_ef       = (const float*)d_in[2];
    const float* b_ef       = (const float*)d_in[3];
    const float* W1         = (const float*)d_in[4];
    const float* b1         = (const float*)d_in[5];
    const float* W2         = (const float*)d_in[6];
    const float* b2         = (const float*)d_in[7];
    const int*   src        = (const int*)d_in[8];
    const int*   dst        = (const int*)d_in[9];
    float* out = (float*)d_out;

    char* ws = (char*)d_ws;
    size_t off = 0;
    auto alloc = [&](size_t bytes) {
        off = (off + 255) & ~(size_t)255;
        void* p = ws + off;
        off += bytes;
        return p;
    };

    float* w_raw = (float*)alloc((size_t)NE * 4);
    unsigned short* pos_e = (unsigned short*)alloc((size_t)NE * 2);
    // [NXCD][NN] out-partials followed by [NXCD][NN] in-partials
    unsigned long long* outp = (unsigned long long*)alloc((size_t)NXCD * NN * 8 * 2);
    unsigned long long* inp  = outp + (size_t)NXCD * NN;
    float* fo       = (float*)alloc((size_t)NN * 4);
    float* fi       = (float*)alloc((size_t)NN * 4);
    unsigned short* loc_off = (unsigned short*)alloc((size_t)NXCD * NN * 2);
    int*   din_buf  = (int*)alloc((size_t)NN * 4);
    int*   blk_sums = (int*)alloc((size_t)NB * 4);
    int*   blk_off  = (int*)alloc((size_t)NB * 4);
    int*   row_ptr  = (int*)alloc((size_t)(NN + 1) * 4);
    int2*  csr      = (int2*)alloc((size_t)NE * 8);
    float* t_buf    = (float*)alloc((size_t)NN * 128 * 4);
    float* h_buf    = (float*)alloc((size_t)NN * 128 * 4);

    hipMemsetAsync(outp, 0, (size_t)NXCD * NN * 8 * 2, stream);

    // edge pipeline + independent layer-1 GEMM in one dispatch (VALU overlap)
    fused1_kernel<<<EDGE_BLK + MM_BLK, 256, 0, stream>>>(
        edge_feats, W_ef, b_ef, src, dst, w_raw, pos_e, outp, inp,
        node_feats, W1, t_buf);

    node_norm_kernel<<<NB, 256, 0, stream>>>(outp, inp, fo, fi,
                                             loc_off, din_buf, blk_sums);

    scan_blk_kernel<<<1, 512, 0, stream>>>(blk_sums, blk_off);

    row_ptr_kernel<<<NB, 256, 0, stream>>>(din_buf, blk_off, row_ptr);

    scatter_kernel<<<(NE + 255) / 256, 256, 0, stream>>>(
        w_raw, pos_e, src, dst, fo, fi, row_ptr, loc_off, csr);

    // layer 1 aggregate (+ReLU)
    spmm_kernel<true><<<25000, 256, 0, stream>>>(
        t_buf, row_ptr, csr, b1, h_buf);

    // layer 2: pure GEMM then aggregate
    matmul_kernel<<<MM_BLK, 256, 0, stream>>>(h_buf, W2, t_buf);
    spmm_kernel<false><<<25000, 256, 0, stream>>>(
        t_buf, row_ptr, csr, b2, out);
}

// Round 3
// 665.368 us; speedup vs baseline: 1.0563x; 1.0563x over previous
//
#include <hip/hip_runtime.h>

#define NN 100000
#define NE 1600000
#define EDGE_BLK 1563               // fused1 edge blocks, 1024 edges each
#define MM_BLK 3125                 // NN/32 gemm tiles
#define NBIN 392                    // node bins: bin = node>>8 (256 nodes/bin)
#define NSB 196                     // hist/scatter blocks, 8192 edges each
#define ESB 8192
#define TOTCNT (2*NBIN*NSB)         // 153,664 (dir-major: dst bins then src bins)
#define SCAN_BLKS 151               // ceil(TOTCNT/1024)
#define FIXSCALE 68719476736.0f     // 2^36
#define FIXINV   (1.0 / 68719476736.0)
#define MASK48   0xFFFFFFFFFFFFULL

// ---------------- shared GEMM tile body:  out[32 x 128] = x_tile @ W -------
// norm factors are folded into CSR edge weights, so this is a PURE gemm.
__device__ __forceinline__ void matmul_tile(const float* __restrict__ x,
                                            const float* __restrict__ W,
                                            float* __restrict__ out,
                                            int tile, int tid,
                                            float (*xs)[129], float (*Ws)[128])
{
    int r = tid & 31, cg = tid >> 5;
    float acc[16];
#pragma unroll
    for (int i = 0; i < 16; i++) acc[i] = 0.f;

#pragma unroll
    for (int i = 0; i < 4; i++) {
        int idx = tid + i * 256;
        int rr = idx >> 5;
        int c4 = (idx & 31) << 2;
        *(float4*)&xs[rr][c4] =
            *(const float4*)(x + (size_t)(tile * 32 + rr) * 128 + c4);
    }

#pragma unroll
    for (int kh = 0; kh < 8; kh++) {
        __syncthreads();
#pragma unroll
        for (int i = 0; i < 2; i++) {
            int idx = tid + i * 256;
            int kk = idx >> 5;              // 0..15
            int c4 = (idx & 31) << 2;
            *(float4*)&Ws[kk][c4] =
                *(const float4*)(W + (size_t)(kh * 16 + kk) * 128 + c4);
        }
        __syncthreads();
#pragma unroll
        for (int k = 0; k < 16; k++) {
            float xk = xs[r][kh * 16 + k];
            const float* wr = &Ws[k][cg * 16];
#pragma unroll
            for (int jj = 0; jj < 16; jj++)
                acc[jj] = fmaf(xk, wr[jj], acc[jj]);
        }
    }

    float* op = out + (size_t)(tile * 32 + r) * 128 + cg * 16;
#pragma unroll
    for (int i = 0; i < 4; i++)
        *(float4*)(op + i * 4) =
            make_float4(acc[i*4], acc[i*4+1], acc[i*4+2], acc[i*4+3]);
}

// ---------------- kernel 1: edge weights (pure stream) + layer-1 GEMM ------
// R2 post-mortem: global atomics on gfx950 execute memory-side regardless of
// scope/occupancy (identical +~100MB atomic write-through in R0/R1/R2, both
// occupancy-doubling and per-XCD-scope nulls). R3 removes ALL global atomics:
// edge path is now a pure 102 MB stream computing w_raw; degree sums / CSR
// slots move to the atomic-free binning pipeline below.
__global__ __launch_bounds__(256) void fused1_kernel(
        const float* __restrict__ ef,
        const float* __restrict__ W_ef,
        const float* __restrict__ b_ef,
        float* __restrict__ w_raw,
        const float* __restrict__ node_feats,
        const float* __restrict__ W1,
        float* __restrict__ t_buf)
{
    __shared__ float xs[32][129];     // +1 pad: kills stride-128 bank conflict
    __shared__ float Ws[16][128];     // 16-row K-chunk: 8 KB -> 6 blocks/CU
    int tid = threadIdx.x;

    if (blockIdx.x < EDGE_BLK) {
        int base = blockIdx.x * 1024 + tid;
#pragma unroll
        for (int q = 0; q < 4; q++) {
            int e = base + q * 256;
            if (e >= NE) continue;
            const float4* p = (const float4*)(ef + (size_t)e * 16);
            float acc = b_ef[0];
#pragma unroll
            for (int i = 0; i < 4; i++) {
                float4 v = p[i];
                acc += v.x * W_ef[i*4+0] + v.y * W_ef[i*4+1]
                     + v.z * W_ef[i*4+2] + v.w * W_ef[i*4+3];
            }
            w_raw[e] = acc;
        }
        return;
    }

    matmul_tile(node_feats, W1, t_buf, blockIdx.x - EDGE_BLK, tid, xs, Ws);
}

// ---------------- kernel H: per-block bin histograms (LDS, no globals) -----
// counts layout: flat f = (dir*NBIN + bin)*NSB + blk, dir0 = dst, dir1 = src.
__global__ __launch_bounds__(256) void hist_kernel(
        const int* __restrict__ src, const int* __restrict__ dst,
        unsigned* __restrict__ counts)
{
    __shared__ unsigned hc[2 * NBIN];
    int t = threadIdx.x;
    for (int i = t; i < 2 * NBIN; i += 256) hc[i] = 0;
    __syncthreads();
    int base = blockIdx.x * ESB;
    for (int i = t; i < ESB; i += 256) {
        int e = base + i;
        if (e < NE) {
            atomicAdd(&hc[dst[e] >> 8], 1u);
            atomicAdd(&hc[NBIN + (src[e] >> 8)], 1u);
        }
    }
    __syncthreads();
    for (int i = t; i < 2 * NBIN; i += 256)
        counts[(size_t)i * NSB + blockIdx.x] = hc[i];
}

// ---------------- kernels SA/SB/SC: 3-level exclusive scan of counts -------
__global__ __launch_bounds__(256) void scanA_kernel(unsigned* __restrict__ counts,
                                                    unsigned* __restrict__ blkS)
{
    __shared__ unsigned s[256];
    int t = threadIdx.x;
    size_t base = (size_t)blockIdx.x * 1024 + t * 4;
    unsigned v[4];
#pragma unroll
    for (int i = 0; i < 4; i++) {
        size_t idx = base + i;
        v[i] = (idx < TOTCNT) ? counts[idx] : 0;
    }
    unsigned tsum = v[0] + v[1] + v[2] + v[3];
    s[t] = tsum;
    __syncthreads();
    for (int o = 1; o < 256; o <<= 1) {
        unsigned u = (t >= o) ? s[t - o] : 0;
        __syncthreads();
        s[t] += u;
        __syncthreads();
    }
    unsigned run = s[t] - tsum;        // exclusive
    if (t == 255) blkS[blockIdx.x] = s[255];
#pragma unroll
    for (int i = 0; i < 4; i++) {
        size_t idx = base + i;
        if (idx < TOTCNT) counts[idx] = run;
        run += v[i];
    }
}

__global__ void scanB_kernel(unsigned* __restrict__ blkS)
{
    __shared__ unsigned s[256];
    int t = threadIdx.x;
    unsigned v = (t < SCAN_BLKS) ? blkS[t] : 0;
    s[t] = v;
    __syncthreads();
    for (int o = 1; o < 256; o <<= 1) {
        unsigned u = (t >= o) ? s[t - o] : 0;
        __syncthreads();
        s[t] += u;
        __syncthreads();
    }
    if (t < SCAN_BLKS) blkS[t] = s[t] - v;   // exclusive
}

__global__ __launch_bounds__(256) void scanC_kernel(unsigned* __restrict__ counts,
                                                    const unsigned* __restrict__ blkS)
{
    unsigned add = blkS[blockIdx.x];
    size_t base = (size_t)blockIdx.x * 1024 + threadIdx.x;
#pragma unroll
    for (int i = 0; i < 4; i++) {
        size_t idx = base + i * 256;
        if (idx < TOTCNT) counts[idx] += add;
    }
}

// ---------------- kernel SC2: scatter edges into binned record arrays ------
// LDS cursors seeded from the scanned offsets; LDS atomics (CU-local) replace
// the memory-side global atomics. drec: (src, dstloc, w, 0); srec: (srcloc, w).
__global__ __launch_bounds__(256) void scatter2_kernel(
        const int* __restrict__ src, const int* __restrict__ dst,
        const float* __restrict__ w_raw, const unsigned* __restrict__ offs,
        int4* __restrict__ drec, int2* __restrict__ srec)
{
    __shared__ unsigned cur[2 * NBIN];
    int t = threadIdx.x;
    for (int i = t; i < 2 * NBIN; i += 256)
        cur[i] = offs[(size_t)i * NSB + blockIdx.x];
    __syncthreads();
    int base = blockIdx.x * ESB;
    for (int i = t; i < ESB; i += 256) {
        int e = base + i;
        if (e >= NE) continue;
        int s = src[e], d = dst[e];
        int wbits = __float_as_int(w_raw[e]);
        unsigned p0 = atomicAdd(&cur[d >> 8], 1u);
        drec[p0] = make_int4(s, d & 255, wbits, 0);
        unsigned p1 = atomicAdd(&cur[NBIN + (s >> 8)], 1u);
        srec[p1 - NE] = make_int2(s & 255, wbits);
    }
}

// ---------------- kernel S: src-bin pass -> fo (LDS packed count|fixsum) ---
__global__ __launch_bounds__(256) void srcbin_kernel(
        const int2* __restrict__ srec, const unsigned* __restrict__ offs,
        float* __restrict__ fo)
{
    __shared__ unsigned long long acc[256];
    int t = threadIdx.x, b = blockIdx.x;
    acc[t] = 0ULL;
    __syncthreads();
    size_t flat = (size_t)(NBIN + b) * NSB;
    unsigned start = offs[flat];
    unsigned end = (b == NBIN - 1) ? (unsigned)(2 * (size_t)NE) : offs[flat + NSB];
    for (unsigned i = start + t; i < end; i += 256) {
        int2 r = srec[i - NE];
        float w = __int_as_float(r.y);
        unsigned long long pk = (1ULL << 48) |
            (unsigned long long)(w * FIXSCALE);
        atomicAdd(&acc[r.x], pk);
    }
    __syncthreads();
    int n = b * 256 + t;
    if (n < NN) {
        unsigned long long po = acc[t];
        int dout = (int)(po >> 48);
        float wo = (float)((double)(po & MASK48) * FIXINV);
        float no = 1.0f / sqrtf((float)(dout > 1 ? dout : 1));
        fo[n] = (wo > 0.f) ? no / sqrtf(wo) : 0.f;
    }
}

// ---------------- kernel D: dst-bin pass -> fi, row_ptr, CSR ---------------
// Bin record base == CSR base (bins are contiguous node ranges), so row_ptr
// and CSR placement need only a 256-wide LDS scan — no global scan at all.
__global__ __launch_bounds__(256) void dstbin_kernel(
        const int4* __restrict__ drec, const unsigned* __restrict__ offs,
        const float* __restrict__ fo,
        int* __restrict__ row_ptr, int2* __restrict__ csr)
{
    __shared__ unsigned long long acc[256];
    __shared__ unsigned sc[256];
    __shared__ unsigned cur[256];
    __shared__ float fil[256];
    int t = threadIdx.x, b = blockIdx.x;
    acc[t] = 0ULL;
    __syncthreads();
    size_t flat = (size_t)b * NSB;
    unsigned start = offs[flat];
    unsigned end = offs[flat + NSB];   // dst bin 391's next = src bin 0 = NE
    for (unsigned i = start + t; i < end; i += 256) {
        int4 r = drec[i];
        float w = __int_as_float(r.z);
        unsigned long long pk = (1ULL << 48) |
            (unsigned long long)(w * FIXSCALE);
        atomicAdd(&acc[r.y], pk);
    }
    __syncthreads();
    unsigned cnt = (unsigned)(acc[t] >> 48);
    {
        float wi = (float)((double)(acc[t] & MASK48) * FIXINV);
        float ni = 1.0f / sqrtf((float)((int)cnt > 1 ? (int)cnt : 1));
        fil[t] = (wi > 0.f) ? ni / sqrtf(wi) : 0.f;
    }
    sc[t] = cnt;
    __syncthreads();
    for (int o = 1; o < 256; o <<= 1) {
        unsigned u = (t >= o) ? sc[t - o] : 0;
        __syncthreads();
        sc[t] += u;
        __syncthreads();
    }
    unsigned excl = sc[t] - cnt;
    int n = b * 256 + t;
    if (n < NN) {
        row_ptr[n] = (int)(start + excl);
        if (n == NN - 1) row_ptr[NN] = NE;
    }
    cur[t] = excl;
    __syncthreads();
    for (unsigned i = start + t; i < end; i += 256) {
        int4 r = drec[i];
        unsigned slot = atomicAdd(&cur[r.y], 1u);
        float wn = __int_as_float(r.z) * fo[r.x] * fil[r.y];
        csr[start + slot] = make_int2(r.x, __float_as_int(wn));
    }
}

// ---------------- kernel 5: standalone pure GEMM (layer 2) -----------------
__global__ __launch_bounds__(256) void matmul_kernel(
        const float* __restrict__ x,
        const float* __restrict__ W,
        float* __restrict__ out)
{
    __shared__ float xs[32][129];
    __shared__ float Ws[16][128];
    matmul_tile(x, W, out, blockIdx.x, threadIdx.x, xs, Ws);
}

// ---------------- kernel 6: CSR SpMM, wave per row, shfl-broadcast + ILP ---
template <bool RELU>
__global__ __launch_bounds__(256) void spmm_kernel(
        const float* __restrict__ t,
        const int* __restrict__ row_ptr,
        const int2* __restrict__ csr,
        const float* __restrict__ bias,
        float* __restrict__ out)
{
    int gtid = blockIdx.x * blockDim.x + threadIdx.x;
    int row = gtid >> 6;
    int lane = threadIdx.x & 63;
    if (row >= NN) return;
    int start = row_ptr[row], end = row_ptr[row + 1];
    float ax = 0.f, ay = 0.f;
    const float* tl = t + lane * 2;
    for (int base = start; base < end; base += 64) {
        int idx = base + lane;
        int2 pr = (idx < end) ? csr[idx] : make_int2(0, 0);
        int cnt = end - base; if (cnt > 64) cnt = 64;
        int cnt8 = (cnt + 7) & ~7;
        for (int j = 0; j < cnt8; j += 8) {
#pragma unroll
            for (int u = 0; u < 8; u++) {
                int s = __shfl(pr.x, j + u);
                float w = __int_as_float(__shfl(pr.y, j + u));
                float2 hv = *(const float2*)(tl + ((size_t)s << 7));
                ax = fmaf(w, hv.x, ax);
                ay = fmaf(w, hv.y, ay);
            }
        }
    }
    float ox = ax + bias[lane * 2];
    float oy = ay + bias[lane * 2 + 1];
    if (RELU) { ox = ox > 0.f ? ox : 0.f; oy = oy > 0.f ? oy : 0.f; }
    *(float2*)(out + ((size_t)row << 7) + lane * 2) = make_float2(ox, oy);
}

// ---------------------------------------------------------------------------
extern "C" void kernel_launch(void* const* d_in, const int* in_sizes, int n_in,
                              void* d_out, int out_size, void* d_ws, size_t ws_size,
                              hipStream_t stream)
{
    const float* node_feats = (const float*)d_in[0];
    const float* edge_feats = (const float*)d_in[1];
    const float* W_ef       = (const float*)d_in[2];
    const float* b_ef       = (const float*)d_in[3];
    const float* W1         = (const float*)d_in[4];
    const float* b1         = (const float*)d_in[5];
    const float* W2         = (const float*)d_in[6];
    const float* b2         = (const float*)d_in[7];
    const int*   src        = (const int*)d_in[8];
    const int*   dst        = (const int*)d_in[9];
    float* out = (float*)d_out;

    char* ws = (char*)d_ws;
    size_t off = 0;
    auto alloc = [&](size_t bytes) {
        off = (off + 255) & ~(size_t)255;
        void* p = ws + off;
        off += bytes;
        return p;
    };

    float*    w_raw  = (float*)alloc((size_t)NE * 4);
    unsigned* counts = (unsigned*)alloc((size_t)TOTCNT * 4);
    unsigned* blkS   = (unsigned*)alloc((size_t)SCAN_BLKS * 4);
    int4*     drec   = (int4*)alloc((size_t)NE * 16);
    int2*     srec   = (int2*)alloc((size_t)NE * 8);
    float*    fo     = (float*)alloc((size_t)NN * 4);
    int*      row_ptr= (int*)alloc((size_t)(NN + 1) * 4);
    int2*     csr    = (int2*)alloc((size_t)NE * 8);
    float*    t_buf  = (float*)alloc((size_t)NN * 128 * 4);
    float*    h_buf  = (float*)alloc((size_t)NN * 128 * 4);

    // histogram + scan chain first (independent of w_raw)
    hist_kernel<<<NSB, 256, 0, stream>>>(src, dst, counts);
    scanA_kernel<<<SCAN_BLKS, 256, 0, stream>>>(counts, blkS);
    scanB_kernel<<<1, 256, 0, stream>>>(blkS);
    scanC_kernel<<<SCAN_BLKS, 256, 0, stream>>>(counts, blkS);

    // edge-weight stream + independent layer-1 GEMM in one dispatch
    fused1_kernel<<<EDGE_BLK + MM_BLK, 256, 0, stream>>>(
        edge_feats, W_ef, b_ef, w_raw, node_feats, W1, t_buf);

    scatter2_kernel<<<NSB, 256, 0, stream>>>(src, dst, w_raw, counts, drec, srec);

    srcbin_kernel<<<NBIN, 256, 0, stream>>>(srec, counts, fo);

    dstbin_kernel<<<NBIN, 256, 0, stream>>>(drec, counts, fo, row_ptr, csr);

    // layer 1 aggregate (+ReLU)
    spmm_kernel<true><<<25000, 256, 0, stream>>>(
        t_buf, row_ptr, csr, b1, h_buf);

    // layer 2: pure GEMM then aggregate
    matmul_kernel<<<MM_BLK, 256, 0, stream>>>(h_buf, W2, t_buf);
    spmm_kernel<false><<<25000, 256, 0, stream>>>(
        t_buf, row_ptr, csr, b2, out);
}